// Round 1
// baseline (355.027 us; speedup 1.0000x reference)
//
#include <hip/hip_runtime.h>
#include <math.h>

#define B_ 1024
#define G_ 256
#define K_ 256
#define E_ 64

// ws layout (in floats)
#define OFF_A   ((size_t)0)                         // K*E*E fp32
#define OFF_S   ((size_t)(K_ * E_ * E_))            // K*E*E
#define OFF_Q6  ((size_t)(2 * K_ * E_ * E_))        // K*E*E
#define OFF_V   ((size_t)(3 * K_ * E_ * E_))        // K*E
#define OFF_MSQ (OFF_V + (size_t)K_ * E_)           // K
#define OFF_LIN (OFF_MSQ + (size_t)K_)              // B*K
#define OFF_SC  (OFF_LIN + (size_t)B_ * K_)         // B*K

struct Coef { double c5[6]; double c6[6]; };

// ---------------------------------------------------------------------------
// P1: per k: A = W^T W (E x E, fp64 accum -> fp32), v = W^T m, msq = ||m||^2
// grid K, block 256
__global__ __launch_bounds__(256) void p1_kernel(const float* __restrict__ w,
                                                 const float* __restrict__ mu,
                                                 float* __restrict__ ws) {
    const int k = blockIdx.x;
    const int t = threadIdx.x;
    const int ti = t >> 4, tj = t & 15;
    __shared__ __align__(16) float sW[64 * 65];
    __shared__ float sMu[64];
    __shared__ double dred[256];

    double acc[4][4];
#pragma unroll
    for (int a = 0; a < 4; ++a)
#pragma unroll
        for (int b = 0; b < 4; ++b) acc[a][b] = 0.0;
    double vacc = 0.0;
    double msqacc = 0.0;
    const int e_t = t & 63, p_t = t >> 6;

    for (int gc = 0; gc < 4; ++gc) {
#pragma unroll
        for (int i = 0; i < 16; ++i) {
            int lin = t + 256 * i;
            int gg = lin >> 6, e = lin & 63;
            sW[gg * 65 + e] = w[((size_t)k * G_ + gc * 64 + gg) * E_ + e];
        }
        if (t < 64) sMu[t] = mu[(size_t)(gc * 64 + t) * K_ + k];
        __syncthreads();
#pragma unroll 4
        for (int gg = 0; gg < 64; ++gg) {
            float ra[4], rb[4];
#pragma unroll
            for (int a = 0; a < 4; ++a) ra[a] = sW[gg * 65 + ti * 4 + a];
#pragma unroll
            for (int b = 0; b < 4; ++b) rb[b] = sW[gg * 65 + tj * 4 + b];
#pragma unroll
            for (int a = 0; a < 4; ++a)
#pragma unroll
                for (int b = 0; b < 4; ++b) acc[a][b] += (double)ra[a] * (double)rb[b];
        }
        for (int gg = p_t * 16; gg < p_t * 16 + 16; ++gg)
            vacc += (double)sW[gg * 65 + e_t] * (double)sMu[gg];
        if (t == 255) {
            for (int gg = 0; gg < 64; ++gg) msqacc += (double)sMu[gg] * (double)sMu[gg];
        }
        __syncthreads();
    }
#pragma unroll
    for (int a = 0; a < 4; ++a)
#pragma unroll
        for (int b = 0; b < 4; ++b) {
            int e = ti * 4 + a, f = tj * 4 + b;
            ws[OFF_A + (size_t)k * 4096 + e * 64 + f] = (float)acc[a][b];
        }
    dred[t] = vacc;
    __syncthreads();
    if (t < 64)
        ws[OFF_V + (size_t)k * 64 + t] =
            (float)(dred[t] + dred[t + 64] + dred[t + 128] + dred[t + 192]);
    if (t == 255) ws[OFF_MSQ + k] = (float)msqacc;
}

// ---------------------------------------------------------------------------
// P2: per k: polynomial in A -> Q6 = beta*P6(A), S = beta^2*P5 A P5 - 2 beta P5
// grid K, block 256
__global__ __launch_bounds__(256) void p2_kernel(float* __restrict__ ws, Coef cf) {
    const int k = blockIdx.x;
    const int t = threadIdx.x;
    const int ti = t >> 4, tj = t & 15;
    __shared__ float bufA[64 * 65];
    __shared__ float bufP[64 * 65];

    const float* gA = ws + OFF_A + (size_t)k * 4096;
#pragma unroll
    for (int i = 0; i < 16; ++i) {
        int lin = t + 256 * i;
        bufA[(lin >> 6) * 65 + (lin & 63)] = gA[lin];
    }
    __syncthreads();

    double acc5[4][4], acc6[4][4];
#pragma unroll
    for (int a = 0; a < 4; ++a)
#pragma unroll
        for (int b = 0; b < 4; ++b) {
            int e = ti * 4 + a, f = tj * 4 + b;
            double av = (double)bufA[e * 65 + f];
            double id = (e == f) ? 1.0 : 0.0;
            acc5[a][b] = cf.c5[0] * id + cf.c5[1] * av;
            acc6[a][b] = cf.c6[0] * id + cf.c6[1] * av;
        }

    for (int j = 2; j <= 5; ++j) {
        const float* X = (j == 2) ? bufA : bufP;
        double pw[4][4];
#pragma unroll
        for (int a = 0; a < 4; ++a)
#pragma unroll
            for (int b = 0; b < 4; ++b) pw[a][b] = 0.0;
        for (int l = 0; l < 64; ++l) {
            float xa[4], yb[4];
#pragma unroll
            for (int a = 0; a < 4; ++a) xa[a] = X[(ti * 4 + a) * 65 + l];
#pragma unroll
            for (int b = 0; b < 4; ++b) yb[b] = bufA[l * 65 + tj * 4 + b];
#pragma unroll
            for (int a = 0; a < 4; ++a)
#pragma unroll
                for (int b = 0; b < 4; ++b) pw[a][b] += (double)xa[a] * (double)yb[b];
        }
        __syncthreads();
#pragma unroll
        for (int a = 0; a < 4; ++a)
#pragma unroll
            for (int b = 0; b < 4; ++b)
                bufP[(ti * 4 + a) * 65 + tj * 4 + b] = (float)pw[a][b];
        __syncthreads();
#pragma unroll
        for (int a = 0; a < 4; ++a)
#pragma unroll
            for (int b = 0; b < 4; ++b) {
                if (j <= 4) acc5[a][b] += cf.c5[j] * pw[a][b];
                acc6[a][b] += cf.c6[j] * pw[a][b];
            }
    }

    // Q6 = beta * acc6
    float* gQ6 = ws + OFF_Q6 + (size_t)k * 4096;
#pragma unroll
    for (int a = 0; a < 4; ++a)
#pragma unroll
        for (int b = 0; b < 4; ++b) {
            int e = ti * 4 + a, f = tj * 4 + b;
            gQ6[e * 64 + f] = (float)(0.05 * acc6[a][b]);
        }

    // P5 -> bufP
#pragma unroll
    for (int a = 0; a < 4; ++a)
#pragma unroll
        for (int b = 0; b < 4; ++b)
            bufP[(ti * 4 + a) * 65 + tj * 4 + b] = (float)acc5[a][b];
    __syncthreads();
    // T = A * P5
    double tacc[4][4];
#pragma unroll
    for (int a = 0; a < 4; ++a)
#pragma unroll
        for (int b = 0; b < 4; ++b) tacc[a][b] = 0.0;
    for (int l = 0; l < 64; ++l) {
        float xa[4], yb[4];
#pragma unroll
        for (int a = 0; a < 4; ++a) xa[a] = bufA[(ti * 4 + a) * 65 + l];
#pragma unroll
        for (int b = 0; b < 4; ++b) yb[b] = bufP[l * 65 + tj * 4 + b];
#pragma unroll
        for (int a = 0; a < 4; ++a)
#pragma unroll
            for (int b = 0; b < 4; ++b) tacc[a][b] += (double)xa[a] * (double)yb[b];
    }
    __syncthreads();
#pragma unroll
    for (int a = 0; a < 4; ++a)
#pragma unroll
        for (int b = 0; b < 4; ++b)
            bufA[(ti * 4 + a) * 65 + tj * 4 + b] = (float)tacc[a][b];
    __syncthreads();
    // Sm = P5 * T ; S = beta^2 * Sm - 2 beta * P5
    double sacc[4][4];
#pragma unroll
    for (int a = 0; a < 4; ++a)
#pragma unroll
        for (int b = 0; b < 4; ++b) sacc[a][b] = 0.0;
    for (int l = 0; l < 64; ++l) {
        float xa[4], yb[4];
#pragma unroll
        for (int a = 0; a < 4; ++a) xa[a] = bufP[(ti * 4 + a) * 65 + l];
#pragma unroll
        for (int b = 0; b < 4; ++b) yb[b] = bufA[l * 65 + tj * 4 + b];
#pragma unroll
        for (int a = 0; a < 4; ++a)
#pragma unroll
            for (int b = 0; b < 4; ++b) sacc[a][b] += (double)xa[a] * (double)yb[b];
    }
    float* gS = ws + OFF_S + (size_t)k * 4096;
    const double beta = 0.05;
#pragma unroll
    for (int a = 0; a < 4; ++a)
#pragma unroll
        for (int b = 0; b < 4; ++b) {
            int e = ti * 4 + a, f = tj * 4 + b;
            gS[e * 64 + f] = (float)(beta * beta * sacc[a][b] - 2.0 * beta * acc5[a][b]);
        }
}

// ---------------------------------------------------------------------------
// L1: lin[b,k] = msq[k] - 2 * sum_g img[b,g]*mu[g,k]
// grid (16,4), block 256
__global__ __launch_bounds__(256) void l1_kernel(const float* __restrict__ img,
                                                 const float* __restrict__ mu,
                                                 float* __restrict__ ws) {
    const int b0 = blockIdx.x * 64;
    const int k0 = blockIdx.y * 64;
    const int t = threadIdx.x;
    const int ti = t >> 4, tj = t & 15;
    __shared__ float sI[64 * 65];
    __shared__ float sM[64 * 65];
    float acc[4][4];
#pragma unroll
    for (int a = 0; a < 4; ++a)
#pragma unroll
        for (int b = 0; b < 4; ++b) acc[a][b] = 0.f;

    for (int gc = 0; gc < 4; ++gc) {
#pragma unroll
        for (int i = 0; i < 16; ++i) {
            int lin = t + 256 * i;
            int r = lin >> 6, c = lin & 63;
            sI[r * 65 + c] = img[(size_t)(b0 + r) * G_ + gc * 64 + c];
            sM[r * 65 + c] = mu[(size_t)(gc * 64 + r) * K_ + k0 + c];
        }
        __syncthreads();
#pragma unroll 4
        for (int gg = 0; gg < 64; ++gg) {
            float xa[4], yb[4];
#pragma unroll
            for (int a = 0; a < 4; ++a) xa[a] = sI[(ti * 4 + a) * 65 + gg];
#pragma unroll
            for (int b = 0; b < 4; ++b) yb[b] = sM[gg * 65 + tj * 4 + b];
#pragma unroll
            for (int a = 0; a < 4; ++a)
#pragma unroll
                for (int b = 0; b < 4; ++b) acc[a][b] += xa[a] * yb[b];
        }
        __syncthreads();
    }
#pragma unroll
    for (int a = 0; a < 4; ++a)
#pragma unroll
        for (int b = 0; b < 4; ++b) {
            int kk = k0 + tj * 4 + b;
            ws[OFF_LIN + (size_t)(b0 + ti * 4 + a) * K_ + kk] =
                ws[OFF_MSQ + kk] - 2.0f * acc[a][b];
        }
}

// ---------------------------------------------------------------------------
// G1: per (k, 128-row b tile): U = img * W_k ; u = U - v ; q = u^T S u ;
//     score[b,k] = lin[b,k] + q
// grid (8, K), block 256
__global__ __launch_bounds__(256) void g1_kernel(const float* __restrict__ img,
                                                 const float* __restrict__ w,
                                                 float* __restrict__ ws) {
    const int k = blockIdx.y;
    const int b0 = blockIdx.x * 128;
    const int t = threadIdx.x;
    const int ti = t >> 4, tj = t & 15;
    __shared__ __align__(16) float shBig[128 * 68];  // tiles alias here, then u
    __shared__ __align__(16) float sS[64 * 64];
    __shared__ float sV[64];
    float* imgT = shBig;         // [32][132]
    float* sW = shBig + 4224;    // [32][68]

#pragma unroll
    for (int i = 0; i < 16; ++i)
        sS[t + 256 * i] = ws[OFF_S + (size_t)k * 4096 + t + 256 * i];
    if (t < 64) sV[t] = ws[OFF_V + (size_t)k * 64 + t];

    float acc[8][4];
#pragma unroll
    for (int a = 0; a < 8; ++a)
#pragma unroll
        for (int b = 0; b < 4; ++b) acc[a][b] = 0.f;

    for (int gc = 0; gc < 8; ++gc) {
        __syncthreads();
#pragma unroll
        for (int i = 0; i < 16; ++i) {
            int lin = t + 256 * i;
            int r = lin >> 5, gg = lin & 31;
            imgT[gg * 132 + r] = img[(size_t)(b0 + r) * G_ + gc * 32 + gg];
        }
#pragma unroll
        for (int i = 0; i < 8; ++i) {
            int lin = t + 256 * i;
            int gg = lin >> 6, e = lin & 63;
            sW[gg * 68 + e] = w[((size_t)k * G_ + gc * 32 + gg) * E_ + e];
        }
        __syncthreads();
#pragma unroll 2
        for (int gg = 0; gg < 32; ++gg) {
            float4 x0 = *(const float4*)&imgT[gg * 132 + ti * 8];
            float4 x1 = *(const float4*)&imgT[gg * 132 + ti * 8 + 4];
            float4 yv = *(const float4*)&sW[gg * 68 + tj * 4];
            float xs[8] = {x0.x, x0.y, x0.z, x0.w, x1.x, x1.y, x1.z, x1.w};
            float ys[4] = {yv.x, yv.y, yv.z, yv.w};
#pragma unroll
            for (int a = 0; a < 8; ++a)
#pragma unroll
                for (int b = 0; b < 4; ++b) acc[a][b] += xs[a] * ys[b];
        }
    }
    __syncthreads();
    // write u = U - v as [128][68]
#pragma unroll
    for (int a = 0; a < 8; ++a) {
        float4 uv;
        uv.x = acc[a][0] - sV[tj * 4 + 0];
        uv.y = acc[a][1] - sV[tj * 4 + 1];
        uv.z = acc[a][2] - sV[tj * 4 + 2];
        uv.w = acc[a][3] - sV[tj * 4 + 3];
        *(float4*)&shBig[(ti * 8 + a) * 68 + tj * 4] = uv;
    }
    __syncthreads();
    // q = u^T S u ; 2 threads per row
    const int r = t >> 1, h = t & 1;
    const float4* Urow = (const float4*)&shBig[r * 68];
    float q = 0.f;
    for (int i = 0; i < 32; ++i) {
        int e = h * 32 + i;
        const float4* Srow = (const float4*)&sS[e * 64];
        float d = 0.f;
#pragma unroll
        for (int f4 = 0; f4 < 16; ++f4) {
            float4 sv = Srow[f4];
            float4 uv = Urow[f4];
            d += sv.x * uv.x + sv.y * uv.y + sv.z * uv.z + sv.w * uv.w;
        }
        q += shBig[r * 68 + e] * d;
    }
    q += __shfl_xor(q, 1, 64);
    if (h == 0) {
        size_t idx = (size_t)(b0 + r) * K_ + k;
        ws[OFF_SC + idx] = ws[OFF_LIN + idx] + q;
    }
}

// ---------------------------------------------------------------------------
// G2: per b: argmin_k score (first-index tie-break), then
//     u = W_k^T img - v ; z6 = Q6 u ; y = W_k z6 + m_k
// grid B, block 256
__global__ __launch_bounds__(256) void g2_kernel(const float* __restrict__ img,
                                                 const float* __restrict__ mu,
                                                 const float* __restrict__ w,
                                                 const float* __restrict__ ws,
                                                 float* __restrict__ out) {
    const int b = blockIdx.x;
    const int t = threadIdx.x;
    __shared__ float rv[4];
    __shared__ int ri[4];
    __shared__ int skbest;
    __shared__ float simg[256];
    __shared__ float up[4][64];
    __shared__ float su[64];
    __shared__ float sz[64];

    float val = ws[OFF_SC + (size_t)b * K_ + t];
    int idx = t;
#pragma unroll
    for (int off = 32; off >= 1; off >>= 1) {
        float ov = __shfl_down(val, off, 64);
        int oi = __shfl_down(idx, off, 64);
        if (ov < val || (ov == val && oi < idx)) { val = ov; idx = oi; }
    }
    if ((t & 63) == 0) { rv[t >> 6] = val; ri[t >> 6] = idx; }
    simg[t] = img[(size_t)b * G_ + t];
    __syncthreads();
    if (t == 0) {
        float bv = rv[0]; int bi = ri[0];
#pragma unroll
        for (int i = 1; i < 4; ++i)
            if (rv[i] < bv || (rv[i] == bv && ri[i] < bi)) { bv = rv[i]; bi = ri[i]; }
        skbest = bi;
    }
    __syncthreads();
    const int kb = skbest;
    const int e = t & 63, p = t >> 6;

    // u partials
    {
        float acc = 0.f;
        const float* wcol = w + ((size_t)kb * G_ + p * 64) * E_ + e;
        for (int g = 0; g < 64; ++g) acc += wcol[(size_t)g * E_] * simg[p * 64 + g];
        up[p][e] = acc;
    }
    __syncthreads();
    if (t < 64)
        su[t] = up[0][t] + up[1][t] + up[2][t] + up[3][t] - ws[OFF_V + (size_t)kb * 64 + t];
    __syncthreads();
    // z6 partials
    {
        float acc = 0.f;
        const float* qrow = ws + OFF_Q6 + (size_t)kb * 4096 + e * 64 + p * 16;
#pragma unroll
        for (int f = 0; f < 16; ++f) acc += qrow[f] * su[p * 16 + f];
        up[p][e] = acc;
    }
    __syncthreads();
    if (t < 64) sz[t] = up[0][t] + up[1][t] + up[2][t] + up[3][t];
    __syncthreads();
    // decode row g = t
    {
        float acc = 0.f;
        const float* wrow = w + ((size_t)kb * G_ + t) * E_;
#pragma unroll 8
        for (int e2 = 0; e2 < 64; ++e2) acc += wrow[e2] * sz[e2];
        out[(size_t)b * G_ + t] = acc + mu[(size_t)t * K_ + kb];
    }
}

// ---------------------------------------------------------------------------
static double binomd(int n, int r) {
    double v = 1.0;
    for (int i = 1; i <= r; ++i) v = v * (double)(n - r + i) / (double)i;
    return v;
}

extern "C" void kernel_launch(void* const* d_in, const int* in_sizes, int n_in,
                              void* d_out, int out_size, void* d_ws, size_t ws_size,
                              hipStream_t stream) {
    const float* img = (const float*)d_in[0];
    const float* mu  = (const float*)d_in[1];
    const float* w   = (const float*)d_in[2];
    float* out = (float*)d_out;
    float* ws = (float*)d_ws;

    Coef cf;
    for (int j = 0; j < 6; ++j) { cf.c5[j] = 0.0; cf.c6[j] = 0.0; }
    const double a = 0.95, nb = -0.05;
    for (int i = 0; i <= 5; ++i) {
        for (int j = 0; j <= i; ++j) {
            double term = binomd(i, j) * pow(a, (double)(i - j)) * pow(nb, (double)j);
            cf.c6[j] += term;
            if (i <= 4) cf.c5[j] += term;
        }
    }

    hipLaunchKernelGGL(p1_kernel, dim3(K_), dim3(256), 0, stream, w, mu, ws);
    hipLaunchKernelGGL(p2_kernel, dim3(K_), dim3(256), 0, stream, ws, cf);
    hipLaunchKernelGGL(l1_kernel, dim3(16, 4), dim3(256), 0, stream, img, mu, ws);
    hipLaunchKernelGGL(g1_kernel, dim3(8, K_), dim3(256), 0, stream, img, w, ws);
    hipLaunchKernelGGL(g2_kernel, dim3(B_), dim3(256), 0, stream, img, mu, w, ws, out);
}